// Round 11
// baseline (169.566 us; speedup 1.0000x reference)
//
#include <hip/hip_runtime.h>
#include <hip/hip_cooperative_groups.h>
#include <float.h>
#include <math.h>

namespace cg = cooperative_groups;

#define BATCH 4
#define NPTS 4096
#define BLK 256
#define QCH 4                      // queries/thread, chamfer
#define QR 2                       // queries/thread, repulsion
#define SEG_CH 32                  // chamfer segments (128 pts)
#define SEG_R 32                   // repulsion segments (128 pts)
#define TPTS 128
#define H2 (0.03f * 0.03f)
#define RADIUS_C 0.07f
#define EPS_C 1e-12f
#define T2 0.05f                   // rep d^2 cutoff: excluded contribs ~1e-25
#define NQ (BATCH * NPTS)          // 16384
#define NCH (2 * NQ)               // 32768 chamfer (type,b,q) rows

// d_ws (12 MB):
//   hdr    : float accum[2] + uint cnt + pad (16 B)  @ 0  (zeroed by blk 0)
//   minseg : float [SEG_CH][NCH]   (4 MB)            @ 16
//   top4   : float4[SEG_R][NQ]     (8 MB)            @ 16 + 4 MB
//
// R9 post-mortem: cross-query gate (min_k h vs max_k m3) is sloppy by the
// |q|^2 spread (O(1) >> T2) -> fired always; and 1024 non-uniform blocks
// re-created the tail. This round: R8's verified decomposition (per-query
// gate, uniform 128-target units) fused into ONE cooperative kernel:
// block i does chamfer unit i then repulsion unit i (uniform duration),
// grid.sync(), then blocks 0..191 merge. Saves a dispatch + merge ramp.

template <bool EXCL>
__device__ __forceinline__ void rep_loop(
    const float4* __restrict__ s, int base, int q0, int q1,
    float nx0, float ny0, float nz0, float nx1, float ny1, float nz1,
    float& a0, float& a1, float& a2, float& a3,
    float& b0, float& b1, float& b2, float& b3)
{
    #pragma unroll 2
    for (int j = 0; j < TPTS; ++j) {
        float4 t = s[j];
        float h0 = fmaf(nx0, t.x, fmaf(ny0, t.y, fmaf(nz0, t.z, t.w)));
        float h1 = fmaf(nx1, t.x, fmaf(ny1, t.y, fmaf(nz1, t.z, t.w)));
        if (EXCL) {
            h0 = (base + j == q0) ? FLT_MAX : h0;          // exclude self
            h1 = (base + j == q1) ? FLT_MAX : h1;
        }
        if (__any((h0 < a3) | (h1 < b3))) {                // per-query-correct gate
            float n0 = fminf(a0, h0);  float u0 = fmaxf(a0, h0);
            float n1 = fminf(a1, u0);  float u1 = fmaxf(a1, u0);
            float n2 = fminf(a2, u1);  float u2 = fmaxf(a2, u1);
            float n3 = fminf(a3, u2);
            a0 = n0; a1 = n1; a2 = n2; a3 = n3;
            float p0 = fminf(b0, h1);  float w0 = fmaxf(b0, h1);
            float p1 = fminf(b1, w0);  float w1 = fmaxf(b1, w0);
            float p2 = fminf(b2, w1);  float w2 = fmaxf(b2, w1);
            float p3 = fminf(b3, w2);
            b0 = p0; b1 = p1; b2 = p2; b3 = p3;
        }
    }
}

// 1024 blocks x 256 (cooperative). Block i: chamfer unit i, rep unit i,
// grid sync, then blocks 0..191 merge + fenced finalize.
__global__ __launch_bounds__(BLK, 4) void fused_kernel(
    const float* __restrict__ pred, const float* __restrict__ gt,
    float* __restrict__ minseg, float4* __restrict__ top4,
    unsigned int* __restrict__ hdr, float* __restrict__ out)
{
    __shared__ float4 s[TPTS];     // 2 KB
    __shared__ float warr[BLK / 64];

    const int id = blockIdx.x;     // [0, 1024)
    if (id == 0 && threadIdx.x < 4)
        hdr[threadIdx.x] = 0u;     // accum[2] + cnt; visible after grid.sync()

    // ---------- chamfer unit: qblk=id&3, type=(id>>2)&1, b=(id>>3)&3, seg=id>>5
    {
        const int qblk = id & 3, type = (id >> 2) & 1, b = (id >> 3) & 3, seg = id >> 5;
        const float* qbase = type ? gt : pred;
        const float* tbase = type ? pred : gt;

        if (threadIdx.x < 64) {    // stage 128 targets, |t|^2 on the fly
            const float2* g2 = (const float2*)(tbase + ((size_t)b * NPTS + seg * TPTS) * 3);
            float2 a = g2[3 * threadIdx.x + 0];
            float2 c = g2[3 * threadIdx.x + 1];
            float2 e = g2[3 * threadIdx.x + 2];
            float t20 = fmaf(a.x, a.x, fmaf(a.y, a.y, c.x * c.x));
            float t21 = fmaf(c.y, c.y, fmaf(e.x, e.x, e.y * e.y));
            s[2 * threadIdx.x + 0] = make_float4(a.x, a.y, c.x, t20);
            s[2 * threadIdx.x + 1] = make_float4(c.y, e.x, e.y, t21);
        }
        __syncthreads();

        const int q0 = qblk * (BLK * QCH) + threadIdx.x;
        float nx[QCH], ny[QCH], nz[QCH], q2[QCH], mn[QCH];
        #pragma unroll
        for (int k = 0; k < QCH; ++k) {
            const float* q = qbase + ((size_t)b * NPTS + q0 + k * BLK) * 3;
            float qx = q[0], qy = q[1], qz = q[2];
            q2[k] = fmaf(qx, qx, fmaf(qy, qy, qz * qz));
            nx[k] = -2.f * qx; ny[k] = -2.f * qy; nz[k] = -2.f * qz;
            mn[k] = FLT_MAX;
        }
        #pragma unroll 2
        for (int j = 0; j < TPTS; j += 2) {
            float4 t0 = s[j], t1 = s[j + 1];
            #pragma unroll
            for (int k = 0; k < QCH; ++k) {
                float h0 = fmaf(nx[k], t0.x, fmaf(ny[k], t0.y, fmaf(nz[k], t0.z, t0.w)));
                float h1 = fmaf(nx[k], t1.x, fmaf(ny[k], t1.y, fmaf(nz[k], t1.z, t1.w)));
                mn[k] = fminf(fminf(mn[k], h0), h1);       // -> v_min3_f32
            }
        }
        float* row = minseg + (size_t)seg * NCH + (type * BATCH + b) * NPTS;
        #pragma unroll
        for (int k = 0; k < QCH; ++k)
            row[q0 + k * BLK] = mn[k] + q2[k];
    }
    __syncthreads();               // protect s before re-staging

    // ---------- repulsion unit: qblk=id&7, b=(id>>3)&3, seg=id>>5
    {
        const int qblk = id & 7, b = (id >> 3) & 3, seg = id >> 5;

        if (threadIdx.x < 64) {    // stage 128 pred targets
            const float2* g2 = (const float2*)(pred + ((size_t)b * NPTS + seg * TPTS) * 3);
            float2 a = g2[3 * threadIdx.x + 0];
            float2 c = g2[3 * threadIdx.x + 1];
            float2 e = g2[3 * threadIdx.x + 2];
            float t20 = fmaf(a.x, a.x, fmaf(a.y, a.y, c.x * c.x));
            float t21 = fmaf(c.y, c.y, fmaf(e.x, e.x, e.y * e.y));
            s[2 * threadIdx.x + 0] = make_float4(a.x, a.y, c.x, t20);
            s[2 * threadIdx.x + 1] = make_float4(c.y, e.x, e.y, t21);
        }
        __syncthreads();

        const int q0 = qblk * (BLK * QR) + threadIdx.x;
        const int q1 = q0 + BLK;
        const float* qa = pred + ((size_t)b * NPTS + q0) * 3;
        const float* qb = pred + ((size_t)b * NPTS + q1) * 3;
        float qx0 = qa[0], qy0 = qa[1], qz0 = qa[2];
        float qx1 = qb[0], qy1 = qb[1], qz1 = qb[2];
        float q20 = fmaf(qx0, qx0, fmaf(qy0, qy0, qz0 * qz0));
        float q21 = fmaf(qx1, qx1, fmaf(qy1, qy1, qz1 * qz1));
        float nx0 = -2.f * qx0, ny0 = -2.f * qy0, nz0 = -2.f * qz0;
        float nx1 = -2.f * qx1, ny1 = -2.f * qy1, nz1 = -2.f * qz1;

        float a0 = T2 - q20, a1 = a0, a2 = a0, a3 = a0;    // h<T2-q2 <=> d2<T2
        float b0 = T2 - q21, b1 = b0, b2 = b0, b3 = b0;
        const int base = seg * TPTS;
        // queries [qblk*512,+512) overlap targets [seg*128,+128) iff seg>>2==qblk
        if ((seg >> 2) == qblk)
            rep_loop<true >(s, base, q0, q1, nx0, ny0, nz0, nx1, ny1, nz1,
                            a0, a1, a2, a3, b0, b1, b2, b3);
        else
            rep_loop<false>(s, base, q0, q1, nx0, ny0, nz0, nx1, ny1, nz1,
                            a0, a1, a2, a3, b0, b1, b2, b3);

        float4* dst = top4 + (size_t)seg * NQ + b * NPTS;
        dst[q0] = make_float4(a0 + q20, a1 + q20, a2 + q20, a3 + q20);
        dst[q1] = make_float4(b0 + q21, b1 + q21, b2 + q21, b3 + q21);
    }

    cg::this_grid().sync();        // all partials visible device-wide

    // ---------- merge phase: blocks [0,128) chamfer sum, [128,192) rep eval
    if (blockIdx.x >= 192) return;
    float contrib;
    int which;
    if (blockIdx.x < NCH / BLK) {
        int i = blockIdx.x * BLK + threadIdx.x;            // [0, 32768)
        float m = minseg[i];
        #pragma unroll 8
        for (int sg = 1; sg < SEG_CH; ++sg)
            m = fminf(m, minseg[(size_t)sg * NCH + i]);
        contrib = fmaxf(m, 0.f);                           // clamp as in reference
        which = 0;
    } else {
        int i = (blockIdx.x - NCH / BLK) * BLK + threadIdx.x;  // [0, 16384)
        float m0 = FLT_MAX, m1 = FLT_MAX, m2 = FLT_MAX, m3 = FLT_MAX;
        #pragma unroll 4
        for (int sg = 0; sg < SEG_R; ++sg) {
            float4 v = top4[(size_t)sg * NQ + i];
            const float vals[4] = {v.x, v.y, v.z, v.w};
            #pragma unroll
            for (int k = 0; k < 4; ++k) {
                float h = vals[k];
                float n0 = fminf(m0, h);  float u0 = fmaxf(m0, h);
                float n1 = fminf(m1, u0); float u1 = fmaxf(m1, u0);
                float n2 = fminf(m2, u1); float u2 = fmaxf(m2, u1);
                float n3 = fminf(m3, u2);
                m0 = n0; m1 = n1; m2 = n2; m3 = n3;
            }
        }
        contrib = 0.f;
        const float ms[4] = {m0, m1, m2, m3};
        #pragma unroll
        for (int k = 0; k < 4; ++k) {
            float d2 = fmaxf(ms[k], EPS_C);
            float d  = sqrtf(d2);
            contrib += (RADIUS_C - d) * expf(-d2 * (1.f / H2));
        }
        which = 1;
    }
    #pragma unroll
    for (int off = 32; off > 0; off >>= 1)
        contrib += __shfl_down(contrib, off, 64);
    if ((threadIdx.x & 63) == 0) warr[threadIdx.x >> 6] = contrib;
    __syncthreads();
    if (threadIdx.x == 0) {
        float bs = warr[0] + warr[1] + warr[2] + warr[3];
        float* accum = (float*)hdr;
        atomicAdd(&accum[which], bs);
        __threadfence();
        unsigned int old = atomicAdd(&hdr[2], 1u);
        if (old == 191u) {                                  // last merge block
            float a0 = atomicAdd(&accum[0], 0.f);           // coherent read
            float a1 = atomicAdd(&accum[1], 0.f);
            out[0] = 100.f * a0 * (1.f / NQ);
            out[1] = a1 * (1.f / (NQ * 4));
        }
    }
}

extern "C" void kernel_launch(void* const* d_in, const int* in_sizes, int n_in,
                              void* d_out, int out_size, void* d_ws, size_t ws_size,
                              hipStream_t stream)
{
    const float* pred = (const float*)d_in[0];
    const float* gt   = (const float*)d_in[1];

    unsigned int* hdr    = (unsigned int*)d_ws;
    float*        minseg = (float*)((char*)d_ws + 16);
    float4*       top4   = (float4*)((char*)d_ws + 16 + (size_t)SEG_CH * NCH * sizeof(float));
    float*        outp   = (float*)d_out;

    void* args[] = {(void*)&pred, (void*)&gt, (void*)&minseg,
                    (void*)&top4, (void*)&hdr, (void*)&outp};
    hipLaunchCooperativeKernel((void*)fused_kernel, dim3(1024), dim3(BLK),
                               args, 0, stream);
}

// Round 12
// 111.132 us; speedup vs baseline: 1.5258x; 1.5258x over previous
//
#include <hip/hip_runtime.h>
#include <float.h>
#include <math.h>

#define BATCH 4
#define NPTS 4096
#define BLK 256
#define QCH 8                      // queries/thread, chamfer: VALU 28 ~ LDS 24 CU-cyc
#define QR 4                       // queries/thread, repulsion: VALU ~22 ~ LDS 24
#define SEG_CH 32                  // 128-pt segments, both phases
#define SEG_R 32
#define TPTS 128
#define H2 (0.03f * 0.03f)
#define RADIUS_C 0.07f
#define EPS_C 1e-12f
#define T2 0.05f                   // rep d^2 cutoff: excluded contribs ~1e-25
#define NQ (BATCH * NPTS)          // 16384
#define NCH (2 * NQ)               // 32768 chamfer (type,b,q) rows

// d_ws (12 MB):
//   hdr    : float accum[2] + uint cnt + pad (16 B)  @ 0  (zeroed by blk 0)
//   minseg : float [SEG_CH][NCH]   (4 MB)            @ 16
//   top4   : float4[SEG_R][NQ]     (8 MB)            @ 16 + 4 MB
//
// R10 post-mortem: grid.sync() costs ~60us on 8 XCDs -> back to 2 kernels.
// Correct pipe count (h = 3 FMA): chamfer QCH=8 and rep QR=4 balance the
// broadcast ds_read_b128 (~12 CU-cyc) against VALU. 1024 blocks (512 ch +
// 512 rep, even/odd interleave), near-uniform duration, 4 blocks/CU.
// Rep gate is PER-QUERY (h_k vs its own m3_k; R9's max-mixing bug avoided);
// insert is a branchless no-op for non-improving h, so OR-combining is exact.

template <bool EXCL>
__device__ __forceinline__ void rep_loop(
    const float4* __restrict__ s, int base, const int* qk,
    const float* nx, const float* ny, const float* nz,
    float m[QR][4])
{
    for (int j = 0; j < TPTS; ++j) {
        float4 t = s[j];
        float h[QR];
        #pragma unroll
        for (int k = 0; k < QR; ++k) {
            h[k] = fmaf(nx[k], t.x, fmaf(ny[k], t.y, fmaf(nz[k], t.z, t.w)));
            if (EXCL) h[k] = (base + j == qk[k]) ? FLT_MAX : h[k];
        }
        bool cand = (h[0] < m[0][3]) | (h[1] < m[1][3])
                  | (h[2] < m[2][3]) | (h[3] < m[3][3]);   // per-query compares
        if (__any(cand)) {                                  // fires only for d2<T2
            #pragma unroll
            for (int k = 0; k < QR; ++k) {
                float n0 = fminf(m[k][0], h[k]); float u0 = fmaxf(m[k][0], h[k]);
                float n1 = fminf(m[k][1], u0);   float u1 = fmaxf(m[k][1], u0);
                float n2 = fminf(m[k][2], u1);   float u2 = fmaxf(m[k][2], u1);
                float n3 = fminf(m[k][3], u2);
                m[k][0] = n0; m[k][1] = n1; m[k][2] = n2; m[k][3] = n3;
            }
        }
    }
}

// 1024 blocks: even bid = chamfer id=bid>>1: qblk=id&1,type=(id>>1)&1,
//   b=(id>>2)&3, seg=id>>4  (2*2*4*32 = 512)
// odd bid = repulsion id=bid>>1: qblk=id&3, b=(id>>2)&3, seg=id>>4 (512)
__global__ __launch_bounds__(BLK) void partial_kernel(
    const float* __restrict__ pred, const float* __restrict__ gt,
    float* __restrict__ minseg, float4* __restrict__ top4,
    unsigned int* __restrict__ hdr)
{
    __shared__ float4 s[TPTS];     // 2 KB

    if (blockIdx.x == 0 && threadIdx.x < 4)
        hdr[threadIdx.x] = 0u;     // zero accum[2]+cnt for merge

    const int isrep = blockIdx.x & 1;
    const int id    = blockIdx.x >> 1;       // [0, 512)

    int type, b, qblk, seg;
    if (!isrep) {
        qblk = id & 1; type = (id >> 1) & 1; b = (id >> 2) & 3; seg = id >> 4;
    } else {
        qblk = id & 3; type = 2;             b = (id >> 2) & 3; seg = id >> 4;
    }
    const float* qbase = (type == 1) ? gt : pred;
    const float* tbase = (type == 0) ? gt : pred;

    // stage 128 targets: threads 0..63, 2 points each, |t|^2 on the fly
    if (threadIdx.x < 64) {
        const float2* g2 = (const float2*)(tbase + ((size_t)b * NPTS + seg * TPTS) * 3);
        float2 a = g2[3 * threadIdx.x + 0];
        float2 c = g2[3 * threadIdx.x + 1];
        float2 e = g2[3 * threadIdx.x + 2];
        float t20 = fmaf(a.x, a.x, fmaf(a.y, a.y, c.x * c.x));
        float t21 = fmaf(c.y, c.y, fmaf(e.x, e.x, e.y * e.y));
        s[2 * threadIdx.x + 0] = make_float4(a.x, a.y, c.x, t20);
        s[2 * threadIdx.x + 1] = make_float4(c.y, e.x, e.y, t21);
    }
    __syncthreads();

    if (!isrep) {
        const int q0 = qblk * (BLK * QCH) + threadIdx.x;   // qblk in {0,1}
        float nx[QCH], ny[QCH], nz[QCH], q2[QCH], mn[QCH];
        #pragma unroll
        for (int k = 0; k < QCH; ++k) {
            const float* q = qbase + ((size_t)b * NPTS + q0 + k * BLK) * 3;
            float qx = q[0], qy = q[1], qz = q[2];
            q2[k] = fmaf(qx, qx, fmaf(qy, qy, qz * qz));
            nx[k] = -2.f * qx; ny[k] = -2.f * qy; nz[k] = -2.f * qz;
            mn[k] = FLT_MAX;
        }
        #pragma unroll 2
        for (int j = 0; j < TPTS; j += 2) {
            float4 t0 = s[j], t1 = s[j + 1];
            #pragma unroll
            for (int k = 0; k < QCH; ++k) {
                float h0 = fmaf(nx[k], t0.x, fmaf(ny[k], t0.y, fmaf(nz[k], t0.z, t0.w)));
                float h1 = fmaf(nx[k], t1.x, fmaf(ny[k], t1.y, fmaf(nz[k], t1.z, t1.w)));
                mn[k] = fminf(fminf(mn[k], h0), h1);       // -> v_min3_f32
            }
        }
        float* row = minseg + (size_t)seg * NCH + (type * BATCH + b) * NPTS;
        #pragma unroll
        for (int k = 0; k < QCH; ++k)
            row[q0 + k * BLK] = mn[k] + q2[k];
    } else {
        int qk[QR];
        float nx[QR], ny[QR], nz[QR], q2[QR], m[QR][4];
        const int q0 = qblk * (BLK * QR) + threadIdx.x;    // qblk in [0,4)
        #pragma unroll
        for (int k = 0; k < QR; ++k) {
            qk[k] = q0 + k * BLK;
            const float* q = qbase + ((size_t)b * NPTS + qk[k]) * 3;
            float qx = q[0], qy = q[1], qz = q[2];
            q2[k] = fmaf(qx, qx, fmaf(qy, qy, qz * qz));
            nx[k] = -2.f * qx; ny[k] = -2.f * qy; nz[k] = -2.f * qz;
            // h-space cutoff init: h < T2 - q2  <=>  d2 < T2
            m[k][0] = m[k][1] = m[k][2] = m[k][3] = T2 - q2[k];
        }
        const int base = seg * TPTS;
        // queries [qblk*1024,+1024) overlap targets [seg*128,+128) iff seg>>3==qblk
        if ((seg >> 3) == qblk)
            rep_loop<true >(s, base, qk, nx, ny, nz, m);
        else
            rep_loop<false>(s, base, qk, nx, ny, nz, m);

        float4* dst = top4 + (size_t)seg * NQ + b * NPTS;
        #pragma unroll
        for (int k = 0; k < QR; ++k)
            dst[qk[k]] = make_float4(m[k][0] + q2[k], m[k][1] + q2[k],
                                     m[k][2] + q2[k], m[k][3] + q2[k]);
    }
}

// 192 blocks: [0,128) chamfer sum; [128,192) repulsion merge+eval.
// Last block (fenced atomic counter) finalizes both outputs.
__global__ __launch_bounds__(BLK) void merge_kernel(
    const float* __restrict__ minseg, const float4* __restrict__ top4,
    unsigned int* __restrict__ hdr, float* __restrict__ out)
{
    __shared__ float warr[BLK / 64];
    float contrib;
    int which;
    if (blockIdx.x < NCH / BLK) {
        int i = blockIdx.x * BLK + threadIdx.x;            // [0, 32768)
        float m = minseg[i];
        #pragma unroll 8
        for (int sg = 1; sg < SEG_CH; ++sg)
            m = fminf(m, minseg[(size_t)sg * NCH + i]);
        contrib = fmaxf(m, 0.f);                           // clamp as in reference
        which = 0;
    } else {
        int i = (blockIdx.x - NCH / BLK) * BLK + threadIdx.x;  // [0, 16384)
        float m0 = FLT_MAX, m1 = FLT_MAX, m2 = FLT_MAX, m3 = FLT_MAX;
        #pragma unroll 4
        for (int sg = 0; sg < SEG_R; ++sg) {
            float4 v = top4[(size_t)sg * NQ + i];
            const float vals[4] = {v.x, v.y, v.z, v.w};
            #pragma unroll
            for (int k = 0; k < 4; ++k) {
                float h = vals[k];
                float n0 = fminf(m0, h);  float u0 = fmaxf(m0, h);
                float n1 = fminf(m1, u0); float u1 = fmaxf(m1, u0);
                float n2 = fminf(m2, u1); float u2 = fmaxf(m2, u1);
                float n3 = fminf(m3, u2);
                m0 = n0; m1 = n1; m2 = n2; m3 = n3;
            }
        }
        contrib = 0.f;
        const float ms[4] = {m0, m1, m2, m3};
        #pragma unroll
        for (int k = 0; k < 4; ++k) {
            float d2 = fmaxf(ms[k], EPS_C);
            float d  = sqrtf(d2);
            contrib += (RADIUS_C - d) * expf(-d2 * (1.f / H2));
        }
        which = 1;
    }
    #pragma unroll
    for (int off = 32; off > 0; off >>= 1)
        contrib += __shfl_down(contrib, off, 64);
    if ((threadIdx.x & 63) == 0) warr[threadIdx.x >> 6] = contrib;
    __syncthreads();
    if (threadIdx.x == 0) {
        float bs = warr[0] + warr[1] + warr[2] + warr[3];
        float* accum = (float*)hdr;
        atomicAdd(&accum[which], bs);
        __threadfence();
        unsigned int old = atomicAdd(&hdr[2], 1u);
        if (old == 191u) {                                  // last block finalizes
            float a0 = atomicAdd(&accum[0], 0.f);           // coherent read
            float a1 = atomicAdd(&accum[1], 0.f);
            out[0] = 100.f * a0 * (1.f / NQ);
            out[1] = a1 * (1.f / (NQ * 4));
        }
    }
}

extern "C" void kernel_launch(void* const* d_in, const int* in_sizes, int n_in,
                              void* d_out, int out_size, void* d_ws, size_t ws_size,
                              hipStream_t stream)
{
    const float* pred = (const float*)d_in[0];
    const float* gt   = (const float*)d_in[1];

    unsigned int* hdr    = (unsigned int*)d_ws;
    float*        minseg = (float*)((char*)d_ws + 16);
    float4*       top4   = (float4*)((char*)d_ws + 16 + (size_t)SEG_CH * NCH * sizeof(float));

    partial_kernel<<<1024, BLK, 0, stream>>>(pred, gt, minseg, top4, hdr);
    merge_kernel<<<192, BLK, 0, stream>>>(minseg, top4, hdr, (float*)d_out);
}

// Round 13
// 93.150 us; speedup vs baseline: 1.8204x; 1.1930x over previous
//
#include <hip/hip_runtime.h>
#include <float.h>
#include <math.h>

#define BATCH 4
#define NPTS 4096
#define BLK 256
#define QCH 4                      // queries/thread, chamfer
#define QR 2                       // queries/thread, repulsion
#define SEG_CH 32                  // chamfer segments (128 pts)
#define SEG_R 32                   // repulsion segments (128 pts)
#define TPTS 128                   // targets/segment, both phases
#define H2 (0.03f * 0.03f)
#define RADIUS_C 0.07f
#define EPS_C 1e-12f
#define T2 0.05f                   // rep d^2 cutoff: excluded contribs ~1e-25
#define NQ (BATCH * NPTS)          // 16384
#define NCH (2 * NQ)               // 32768 chamfer (type,b,q) rows

// VERIFIED BEST (R8, 92.9 us total). d_ws (12 MB):
//   hdr    : float accum[2] + uint cnt + pad (16 B)  @ 0  (zeroed by blk 0)
//   minseg : float [SEG_CH][NCH]   (4 MB)            @ 16
//   top4   : float4[SEG_R][NQ]     (8 MB)            @ 16 + 4 MB
//
// Session record: 2048 uniform 128-target interleaved blocks (8 queued/CU,
// continuous refill, no phase tail) beat every alternative tried:
// fatter blocks (R3/R9/R11), bigger segments (R7), cross-query gate (R9),
// cooperative fusion (R10). h = |t|^2 - 2 q.t (reference's expansion);
// rep top-4 regs init to T2-|q|^2 so the insert gate fires only for d2<T2.

template <bool EXCL>
__device__ __forceinline__ void rep_loop(
    const float4* __restrict__ s, int base, int q0, int q1,
    float nx0, float ny0, float nz0, float nx1, float ny1, float nz1,
    float& a0, float& a1, float& a2, float& a3,
    float& b0, float& b1, float& b2, float& b3)
{
    #pragma unroll 2
    for (int j = 0; j < TPTS; ++j) {
        float4 t = s[j];
        float h0 = fmaf(nx0, t.x, fmaf(ny0, t.y, fmaf(nz0, t.z, t.w)));
        float h1 = fmaf(nx1, t.x, fmaf(ny1, t.y, fmaf(nz1, t.z, t.w)));
        if (EXCL) {
            h0 = (base + j == q0) ? FLT_MAX : h0;          // exclude self
            h1 = (base + j == q1) ? FLT_MAX : h1;
        }
        if (__any((h0 < a3) | (h1 < b3))) {                // per-query gate, rare
            float n0 = fminf(a0, h0);  float u0 = fmaxf(a0, h0);
            float n1 = fminf(a1, u0);  float u1 = fmaxf(a1, u0);
            float n2 = fminf(a2, u1);  float u2 = fmaxf(a2, u1);
            float n3 = fminf(a3, u2);
            a0 = n0; a1 = n1; a2 = n2; a3 = n3;
            float p0 = fminf(b0, h1);  float w0 = fmaxf(b0, h1);
            float p1 = fminf(b1, w0);  float w1 = fmaxf(b1, w0);
            float p2 = fminf(b2, w1);  float w2 = fmaxf(b2, w1);
            float p3 = fminf(b3, w2);
            b0 = p0; b1 = p1; b2 = p2; b3 = p3;
        }
    }
}

// 2048 blocks: even bid = chamfer (qblk4 x type2 x b4 x seg32 = 1024),
//              odd  bid = repulsion (qblk8 x b4 x seg32 = 1024).
__global__ __launch_bounds__(BLK) void partial_kernel(
    const float* __restrict__ pred, const float* __restrict__ gt,
    float* __restrict__ minseg, float4* __restrict__ top4,
    unsigned int* __restrict__ hdr)
{
    __shared__ float4 s[TPTS];     // 128 x (x,y,z,|t|^2) = 2 KB

    if (blockIdx.x == 0 && threadIdx.x < 4)
        hdr[threadIdx.x] = 0u;     // zero accum[2]+cnt for merge

    const int bid   = blockIdx.x;
    const int isrep = bid & 1;
    const int id    = bid >> 1;    // [0,1024)

    int type, b, qblk, seg;
    if (!isrep) {
        qblk = id & 3; type = (id >> 2) & 1; b = (id >> 3) & 3; seg = id >> 5;
    } else {
        qblk = id & 7; type = 2;             b = (id >> 3) & 3; seg = id >> 5;
    }
    const float* qbase = (type == 1) ? gt : pred;
    const float* tbase = (type == 0) ? gt : pred;

    // stage 128 targets: threads 0..63, 2 points each, |t|^2 on the fly
    if (threadIdx.x < 64) {
        const float2* g2 = (const float2*)(tbase + ((size_t)b * NPTS + seg * TPTS) * 3);
        float2 a = g2[3 * threadIdx.x + 0];
        float2 c = g2[3 * threadIdx.x + 1];
        float2 e = g2[3 * threadIdx.x + 2];
        float t20 = fmaf(a.x, a.x, fmaf(a.y, a.y, c.x * c.x));
        float t21 = fmaf(c.y, c.y, fmaf(e.x, e.x, e.y * e.y));
        s[2 * threadIdx.x + 0] = make_float4(a.x, a.y, c.x, t20);
        s[2 * threadIdx.x + 1] = make_float4(c.y, e.x, e.y, t21);
    }
    __syncthreads();

    if (!isrep) {
        const int q0 = qblk * (BLK * QCH) + threadIdx.x;
        float nx[QCH], ny[QCH], nz[QCH], q2[QCH], mn[QCH];
        #pragma unroll
        for (int k = 0; k < QCH; ++k) {
            const float* q = qbase + ((size_t)b * NPTS + q0 + k * BLK) * 3;
            float qx = q[0], qy = q[1], qz = q[2];
            q2[k] = fmaf(qx, qx, fmaf(qy, qy, qz * qz));
            nx[k] = -2.f * qx; ny[k] = -2.f * qy; nz[k] = -2.f * qz;
            mn[k] = FLT_MAX;
        }
        #pragma unroll 2
        for (int j = 0; j < TPTS; j += 2) {
            float4 t0 = s[j], t1 = s[j + 1];
            #pragma unroll
            for (int k = 0; k < QCH; ++k) {
                float h0 = fmaf(nx[k], t0.x, fmaf(ny[k], t0.y, fmaf(nz[k], t0.z, t0.w)));
                float h1 = fmaf(nx[k], t1.x, fmaf(ny[k], t1.y, fmaf(nz[k], t1.z, t1.w)));
                mn[k] = fminf(fminf(mn[k], h0), h1);       // -> v_min3_f32
            }
        }
        float* row = minseg + (size_t)seg * NCH + (type * BATCH + b) * NPTS;
        #pragma unroll
        for (int k = 0; k < QCH; ++k)
            row[q0 + k * BLK] = mn[k] + q2[k];
    } else {
        const int q0 = qblk * (BLK * QR) + threadIdx.x;
        const int q1 = q0 + BLK;
        const float* qa = qbase + ((size_t)b * NPTS + q0) * 3;
        const float* qb = qbase + ((size_t)b * NPTS + q1) * 3;
        float qx0 = qa[0], qy0 = qa[1], qz0 = qa[2];
        float qx1 = qb[0], qy1 = qb[1], qz1 = qb[2];
        float q20 = fmaf(qx0, qx0, fmaf(qy0, qy0, qz0 * qz0));
        float q21 = fmaf(qx1, qx1, fmaf(qy1, qy1, qz1 * qz1));
        float nx0 = -2.f * qx0, ny0 = -2.f * qy0, nz0 = -2.f * qz0;
        float nx1 = -2.f * qx1, ny1 = -2.f * qy1, nz1 = -2.f * qz1;

        // h-space cutoff init: h < T2 - q2  <=>  d2 < T2
        float a0 = T2 - q20, a1 = a0, a2 = a0, a3 = a0;
        float b0 = T2 - q21, b1 = b0, b2 = b0, b3 = b0;
        const int base = seg * TPTS;
        // queries [qblk*512, +512) overlap targets [seg*128, +128) iff seg>>2==qblk
        if ((seg >> 2) == qblk)
            rep_loop<true >(s, base, q0, q1, nx0, ny0, nz0, nx1, ny1, nz1,
                            a0, a1, a2, a3, b0, b1, b2, b3);
        else
            rep_loop<false>(s, base, q0, q1, nx0, ny0, nz0, nx1, ny1, nz1,
                            a0, a1, a2, a3, b0, b1, b2, b3);

        float4* dst = top4 + (size_t)seg * NQ + b * NPTS;
        dst[q0] = make_float4(a0 + q20, a1 + q20, a2 + q20, a3 + q20);
        dst[q1] = make_float4(b0 + q21, b1 + q21, b2 + q21, b3 + q21);
    }
}

// 192 blocks: [0,128) chamfer sum; [128,192) repulsion merge+eval.
// Last block (fenced atomic counter) finalizes both outputs.
__global__ __launch_bounds__(BLK) void merge_kernel(
    const float* __restrict__ minseg, const float4* __restrict__ top4,
    unsigned int* __restrict__ hdr, float* __restrict__ out)
{
    __shared__ float warr[BLK / 64];
    float contrib;
    int which;
    if (blockIdx.x < NCH / BLK) {
        int i = blockIdx.x * BLK + threadIdx.x;            // [0, 32768)
        float m = minseg[i];
        #pragma unroll 8
        for (int sg = 1; sg < SEG_CH; ++sg)
            m = fminf(m, minseg[(size_t)sg * NCH + i]);
        contrib = fmaxf(m, 0.f);                           // clamp as in reference
        which = 0;
    } else {
        int i = (blockIdx.x - NCH / BLK) * BLK + threadIdx.x;  // [0, 16384)
        float m0 = FLT_MAX, m1 = FLT_MAX, m2 = FLT_MAX, m3 = FLT_MAX;
        #pragma unroll 4
        for (int sg = 0; sg < SEG_R; ++sg) {
            float4 v = top4[(size_t)sg * NQ + i];
            const float vals[4] = {v.x, v.y, v.z, v.w};
            #pragma unroll
            for (int k = 0; k < 4; ++k) {
                float h = vals[k];
                float n0 = fminf(m0, h);  float u0 = fmaxf(m0, h);
                float n1 = fminf(m1, u0); float u1 = fmaxf(m1, u0);
                float n2 = fminf(m2, u1); float u2 = fmaxf(m2, u1);
                float n3 = fminf(m3, u2);
                m0 = n0; m1 = n1; m2 = n2; m3 = n3;
            }
        }
        contrib = 0.f;
        const float ms[4] = {m0, m1, m2, m3};
        #pragma unroll
        for (int k = 0; k < 4; ++k) {
            float d2 = fmaxf(ms[k], EPS_C);
            float d  = sqrtf(d2);
            contrib += (RADIUS_C - d) * expf(-d2 * (1.f / H2));
        }
        which = 1;
    }
    #pragma unroll
    for (int off = 32; off > 0; off >>= 1)
        contrib += __shfl_down(contrib, off, 64);
    if ((threadIdx.x & 63) == 0) warr[threadIdx.x >> 6] = contrib;
    __syncthreads();
    if (threadIdx.x == 0) {
        float bs = warr[0] + warr[1] + warr[2] + warr[3];
        float* accum = (float*)hdr;
        atomicAdd(&accum[which], bs);
        __threadfence();
        unsigned int old = atomicAdd(&hdr[2], 1u);
        if (old == 191u) {                                  // last block finalizes
            float a0 = atomicAdd(&accum[0], 0.f);           // coherent read
            float a1 = atomicAdd(&accum[1], 0.f);
            out[0] = 100.f * a0 * (1.f / NQ);
            out[1] = a1 * (1.f / (NQ * 4));
        }
    }
}

extern "C" void kernel_launch(void* const* d_in, const int* in_sizes, int n_in,
                              void* d_out, int out_size, void* d_ws, size_t ws_size,
                              hipStream_t stream)
{
    const float* pred = (const float*)d_in[0];
    const float* gt   = (const float*)d_in[1];

    unsigned int* hdr    = (unsigned int*)d_ws;
    float*        minseg = (float*)((char*)d_ws + 16);
    float4*       top4   = (float4*)((char*)d_ws + 16 + (size_t)SEG_CH * NCH * sizeof(float));

    partial_kernel<<<2048, BLK, 0, stream>>>(pred, gt, minseg, top4, hdr);
    merge_kernel<<<192, BLK, 0, stream>>>(minseg, top4, hdr, (float*)d_out);
}